// Round 8
// baseline (243.380 us; speedup 1.0000x reference)
//
#include <hip/hip_runtime.h>
#include <hip/hip_bf16.h>

#define B_DIM 16
#define C_DIM 512
#define HW_DIM 4096
#define LN_EPS 1e-5f
#define ATTN_STRIDE 1024  // attn row stride (u16) — aliased into e_part[0]

using bf16 = __hip_bfloat16;
typedef __bf16 v8bf __attribute__((ext_vector_type(8)));
typedef float v4f __attribute__((ext_vector_type(4)));
typedef unsigned short v8us __attribute__((ext_vector_type(8)));
typedef unsigned short v4us __attribute__((ext_vector_type(4)));
using gptr_t = const __attribute__((address_space(1))) void*;
using lptr_t = __attribute__((address_space(3))) void*;

__device__ __forceinline__ unsigned short f2bf(float f) {
  unsigned int u = __float_as_uint(f);
  u = (u + 0x7fffu + ((u >> 16) & 1u)) >> 16;  // RNE
  return (unsigned short)u;
}
__device__ __forceinline__ float bf2f(unsigned short us) {
  return __uint_as_float(((unsigned int)us) << 16);
}

// ---------------- pass 0: pure-stream f32 -> bf16 copy ----------------------
__global__ __launch_bounds__(256) void k_convert(
    const float* __restrict__ x, unsigned short* __restrict__ v) {
  const size_t i0 = ((size_t)blockIdx.x * 256 + threadIdx.x) * 8;
  const size_t step = (size_t)2048 * 256 * 8;  // 4,194,304 elems
#pragma unroll
  for (int it = 0; it < 8; ++it) {
    const size_t base = i0 + (size_t)it * step;
    const float4 f0 = ((const float4*)(x + base))[0];
    const float4 f1 = ((const float4*)(x + base))[1];
    v8us pack;
    pack[0] = f2bf(f0.x); pack[1] = f2bf(f0.y);
    pack[2] = f2bf(f0.z); pack[3] = f2bf(f0.w);
    pack[4] = f2bf(f1.x); pack[5] = f2bf(f1.y);
    pack[6] = f2bf(f1.z); pack[7] = f2bf(f1.w);
    *(v8us*)(v + base) = pack;
  }
}

// ---------------- shared 256x256 8-phase GEMM pieces ------------------------
#define TILE_E (256 * 64)

__device__ __forceinline__ void stage_half8(
    const bf16* __restrict__ g, bf16* l, int k0, int stride, int wave, int lane) {
  const int lrow = lane >> 3, lc = lane & 7;
#pragma unroll
  for (int i = 0; i < 2; ++i) {
    const int row = i * 64 + wave * 8 + lrow;
    __builtin_amdgcn_global_load_lds(
        (gptr_t)(g + (size_t)row * stride + k0 + ((lc ^ (row & 7)) << 3)),
        (lptr_t)(l + (i * 64 + wave * 8) * 64), 16, 0, 0);
  }
}
__device__ __forceinline__ void stage_op2(
    const bf16* __restrict__ g, bf16* l, int k0, int stride, int wave, int lane) {
  stage_half8(g, l, k0, stride, wave, lane);
  stage_half8(g + (size_t)128 * stride, l + 128 * 64, k0, stride, wave, lane);
}
__device__ __forceinline__ v8bf ld_frag8(const bf16* l, int row, int j) {
  return *(const v8bf*)(l + row * 64 + ((j ^ (row & 7)) << 3));
}
// B-side swizzle for the reg-staged transpose path (key varies with BOTH
// n&7 and n>>3 so transposed writes AND fragment reads are conflict-free).
__device__ __forceinline__ v8bf ld_frag8B(const bf16* l, int row, int j) {
  const int key = (row & 7) ^ ((row >> 3) & 7);
  return *(const v8bf*)(l + row * 64 + ((j ^ key) << 3));
}
// 8 gload_lds covering 256 rows x 64 k with 4 waves (gemm2 A-stager).
__device__ __forceinline__ void stageA8(
    const bf16* __restrict__ g, bf16* l, int k0, int stride,
    int w4, int lrow, int lc) {
#pragma unroll
  for (int i = 0; i < 8; ++i) {
    const int row = i * 32 + w4 * 8 + lrow;
    __builtin_amdgcn_global_load_lds(
        (gptr_t)(g + (size_t)row * stride + k0 + ((lc ^ (row & 7)) << 3)),
        (lptr_t)(l + (i * 32 + w4 * 8) * 64), 16, 0, 0);
  }
}
// Transposed B write: thread's 8d x 8n reg block -> [n][k] LDS rows.
__device__ __forceinline__ void bwrite8(
    bf16* lb, const v8us bu[8], int dblk, int n8) {
  unsigned short* lu = (unsigned short*)lb;
#pragma unroll
  for (int j = 0; j < 8; ++j) {
    const int n = n8 + j;
    const int key = (n & 7) ^ ((n >> 3) & 7);
    v8us p;
#pragma unroll
    for (int r = 0; r < 8; ++r) p[r] = bu[r][j];
    *(v8us*)(lu + n * 64 + ((dblk ^ key) << 3)) = p;
  }
}

// K-loop for gemm1 (both operands via global_load_lds), unchanged.
__device__ __forceinline__ void gemm_8ph_loop(
    const bf16* __restrict__ Ab, const bf16* __restrict__ Bb,
    const int strideA, const int strideB, const int kts,
    bf16* smem, const int wave, const int lane, v4f acc[8][4]) {
  const int wm = wave >> 2, wn = wave & 3;
  const int rl = lane & 15, kq = lane >> 4;

  stage_op2(Bb, smem + 2 * TILE_E, 0, strideB, wave, lane);
  stage_op2(Ab, smem, 0, strideA, wave, lane);
  stage_op2(Bb, smem + 3 * TILE_E, 64, strideB, wave, lane);
  stage_op2(Ab, smem + TILE_E, 64, strideA, wave, lane);
  asm volatile("s_waitcnt vmcnt(8)" ::: "memory");
  __builtin_amdgcn_s_barrier();

  v8bf a[4][2], b01[2][2], b23[2][2];
  for (int kt = 0; kt < kts; ++kt) {
    const bf16* LA = smem + (kt & 1) * TILE_E;
    const bf16* LB = smem + (2 + (kt & 1)) * TILE_E;
    bf16* SA = smem + (kt & 1) * TILE_E;
    bf16* SB = smem + (2 + (kt & 1)) * TILE_E;
#pragma unroll
    for (int mi = 0; mi < 4; ++mi)
#pragma unroll
      for (int kk = 0; kk < 2; ++kk)
        a[mi][kk] = ld_frag8(LA, wm * 128 + mi * 16 + rl, kk * 4 + kq);
#pragma unroll
    for (int ni = 0; ni < 2; ++ni)
#pragma unroll
      for (int kk = 0; kk < 2; ++kk)
        b01[ni][kk] = ld_frag8(LB, wn * 64 + ni * 16 + rl, kk * 4 + kq);
    __builtin_amdgcn_s_barrier();
    asm volatile("s_waitcnt lgkmcnt(0)");
    __builtin_amdgcn_s_setprio(1);
#pragma unroll
    for (int kk = 0; kk < 2; ++kk)
#pragma unroll
      for (int mi = 0; mi < 4; ++mi)
#pragma unroll
        for (int ni = 0; ni < 2; ++ni)
          acc[mi][ni] = __builtin_amdgcn_mfma_f32_16x16x32_bf16(
              a[mi][kk], b01[ni][kk], acc[mi][ni], 0, 0, 0);
    __builtin_amdgcn_s_setprio(0);
    __builtin_amdgcn_s_barrier();
#pragma unroll
    for (int ni = 0; ni < 2; ++ni)
#pragma unroll
      for (int kk = 0; kk < 2; ++kk)
        b23[ni][kk] = ld_frag8(LB, wn * 64 + (ni + 2) * 16 + rl, kk * 4 + kq);
    __builtin_amdgcn_s_barrier();
    asm volatile("s_waitcnt lgkmcnt(0)");
    __builtin_amdgcn_s_setprio(1);
#pragma unroll
    for (int kk = 0; kk < 2; ++kk)
#pragma unroll
      for (int mi = 0; mi < 4; ++mi)
#pragma unroll
        for (int ni = 0; ni < 2; ++ni)
          acc[mi][ni + 2] = __builtin_amdgcn_mfma_f32_16x16x32_bf16(
              a[mi][kk], b23[ni][kk], acc[mi][ni + 2], 0, 0, 0);
    __builtin_amdgcn_s_setprio(0);
    __builtin_amdgcn_s_barrier();
#pragma unroll
    for (int mi = 0; mi < 4; ++mi)
#pragma unroll
      for (int kk = 0; kk < 2; ++kk)
        a[mi][kk] = ld_frag8(LA, wm * 128 + (mi + 4) * 16 + rl, kk * 4 + kq);
    if (kt < kts - 2) stage_op2(Bb, SB, (kt + 2) * 64, strideB, wave, lane);
    __builtin_amdgcn_s_barrier();
    asm volatile("s_waitcnt lgkmcnt(0)");
    __builtin_amdgcn_s_setprio(1);
#pragma unroll
    for (int kk = 0; kk < 2; ++kk)
#pragma unroll
      for (int mi = 0; mi < 4; ++mi)
#pragma unroll
        for (int ni = 0; ni < 2; ++ni)
          acc[mi + 4][ni + 2] = __builtin_amdgcn_mfma_f32_16x16x32_bf16(
              a[mi][kk], b23[ni][kk], acc[mi + 4][ni + 2], 0, 0, 0);
    __builtin_amdgcn_s_setprio(0);
    __builtin_amdgcn_s_barrier();
    if (kt < kts - 2) stage_op2(Ab, SA, (kt + 2) * 64, strideA, wave, lane);
    __builtin_amdgcn_s_barrier();
    __builtin_amdgcn_s_setprio(1);
#pragma unroll
    for (int kk = 0; kk < 2; ++kk)
#pragma unroll
      for (int mi = 0; mi < 4; ++mi)
#pragma unroll
        for (int ni = 0; ni < 2; ++ni)
          acc[mi + 4][ni] = __builtin_amdgcn_mfma_f32_16x16x32_bf16(
              a[mi][kk], b01[ni][kk], acc[mi + 4][ni], 0, 0, 0);
    __builtin_amdgcn_s_setprio(0);
    if (kt < kts - 2)
      asm volatile("s_waitcnt vmcnt(8)" ::: "memory");
    else if (kt == kts - 2)
      asm volatile("s_waitcnt vmcnt(0)" ::: "memory");
    __builtin_amdgcn_s_barrier();
  }
}

// Epilogue: acc -> swizzled LDS -> 1KiB-contiguous f32 row stores.
__device__ __forceinline__ void epilogue_bounce(
    v4f acc[8][4], bf16* smem, float* ob, const int out_stride,
    const int wave, const int lane) {
  const int wm = wave >> 2, wn = wave & 3;
  const int rl = lane & 15, kq = lane >> 4;
  float* smf = (float*)smem;  // [128][256] f32
#pragma unroll
  for (int h = 0; h < 2; ++h) {
    if (wm == h) {
#pragma unroll
      for (int mi = 0; mi < 8; ++mi)
#pragma unroll
        for (int ni = 0; ni < 4; ++ni)
#pragma unroll
          for (int rr = 0; rr < 4; ++rr) {
            const int rloc = mi * 16 + kq * 4 + rr;  // 0..127
            const int col = wn * 64 + ni * 16 + rl;
            const int key = rloc & 7;
            smf[rloc * 256 + ((((col >> 2) ^ key) << 2) | (col & 3))] =
                acc[mi][ni][rr];
          }
    }
    __syncthreads();
#pragma unroll
    for (int it = 0; it < 16; ++it) {
      const int rloc = it * 8 + wave;
      const float4 vv =
          *(const float4*)(smf + rloc * 256 + ((lane ^ (rloc & 7)) << 2));
      *(float4*)(ob + (size_t)(h * 128 + rloc) * out_stride + lane * 4) = vv;
    }
    __syncthreads();
  }
}

// ---------------- pass 1: energy = V V^T, 256^2 8-phase, split-K 4 ----------
__global__ __launch_bounds__(512, 2) void k_gemm1(
    const bf16* __restrict__ v, float* __restrict__ e_part) {
  __shared__ __align__(16) bf16 smem[4 * TILE_E];  // 128 KiB
  const int bid = blockIdx.x;
  const int t = (bid & 7) * 32 + (bid >> 3);  // bijective XCD swizzle (256%8==0)
  const int ks = t & 3;
  const int db = (t >> 2) & 1;
  const int cb = (t >> 3) & 1;
  const int b = t >> 4;
  const int tid = threadIdx.x;
  const int wave = tid >> 6, lane = tid & 63;

  const bf16* vb = v + (size_t)b * ((size_t)C_DIM * HW_DIM) + ks * 1024;
  const bf16* Ab = vb + (size_t)(cb * 256) * HW_DIM;
  const bf16* Bb = vb + (size_t)(db * 256) * HW_DIM;

  v4f acc[8][4] = {};
  gemm_8ph_loop(Ab, Bb, HW_DIM, HW_DIM, 16, smem, wave, lane, acc);

  float* ob = e_part + (size_t)ks * ((size_t)B_DIM * C_DIM * C_DIM) +
              (size_t)b * (C_DIM * C_DIM) + (size_t)(cb * 256) * C_DIM + db * 256;
  epilogue_bounce(acc, smem, ob, C_DIM, wave, lane);
}

// ---------------- pass 2: row softmax (sums 4 partials), write bf16 ---------
__global__ __launch_bounds__(256) void k_softmax(
    const float* __restrict__ e_part, unsigned short* __restrict__ attn) {
  const int row = blockIdx.x;  // 0..8191 = b*512 + c
  const size_t bcc = (size_t)B_DIM * C_DIM * C_DIM;
  const float* e0 = e_part + (size_t)row * C_DIM;
  const int tid = threadIdx.x;
  float v0 = 0.f, v1 = 0.f;
#pragma unroll
  for (int p = 0; p < 4; ++p) {
    v0 += e0[p * bcc + tid];
    v1 += e0[p * bcc + tid + 256];
  }
  float mx = fmaxf(v0, v1);
#pragma unroll
  for (int off = 32; off > 0; off >>= 1) mx = fmaxf(mx, __shfl_xor(mx, off));
  __shared__ float rmax[4], rsum[4];
  const int wv = tid >> 6, ln = tid & 63;
  if (ln == 0) rmax[wv] = mx;
  __syncthreads();
  mx = fmaxf(fmaxf(rmax[0], rmax[1]), fmaxf(rmax[2], rmax[3]));
  const float p0 = __expf(v0 - mx), p1 = __expf(v1 - mx);
  float s = p0 + p1;
#pragma unroll
  for (int off = 32; off > 0; off >>= 1) s += __shfl_xor(s, off);
  if (ln == 0) rsum[wv] = s;
  __syncthreads();
  s = rsum[0] + rsum[1] + rsum[2] + rsum[3];
  const float inv = 1.0f / s;
  attn[(size_t)row * ATTN_STRIDE + tid] = f2bf(p0 * inv);
  attn[(size_t)row * ATTN_STRIDE + tid + 256] = f2bf(p1 * inv);
}

// ---------------- pass 3: out = attn @ V, 256^2 8-phase ---------------------
// vt ELIMINATED: B operand is transposed inside the staging path.
// Waves 0-3: B-transposers — load 8x16B rows of v (kt+2) at ph0, in-register
// 8x8 transpose, conflict-free swizzled ds_write_b128 at ph2 (after the B
// buffer's last read at ph1).  Waves 4-7: A-stagers (8 gload_lds at ph3).
// Boundary vmcnt(8) stays exact for A (waves 0-3 have 0 outstanding there:
// compiler drains their loads before the ds_writes).
__global__ __launch_bounds__(512, 2) void k_gemm2(
    const bf16* __restrict__ attn, const bf16* __restrict__ v,
    float* __restrict__ out) {
  __shared__ __align__(16) bf16 smem[4 * TILE_E];  // A0,A1,B0,B1 (128 KiB)
  const int bid = blockIdx.x;
  const int t = (bid & 7) * 64 + (bid >> 3);  // bijective XCD swizzle
  const int b = t >> 5;
  const int cb = (t >> 4) & 1;
  const int nb = t & 15;
  const int tid = threadIdx.x;
  const int wave = tid >> 6, lane = tid & 63;
  const int rl = lane & 15, kq = lane >> 4;
  const int wm = wave >> 2, wn = wave & 3;

  const bf16* Ab = attn + (size_t)(b * C_DIM + cb * 256) * ATTN_STRIDE;
  const bf16* Vb = v + (size_t)b * ((size_t)C_DIM * HW_DIM) + nb * 256;

  const bool isB = (tid < 256);        // waves 0-3 (wave-uniform)
  const int w4 = wave & 3;
  const int lrow = lane >> 3, lc = lane & 7;
  const int dblk = (tid & 255) >> 5;   // 0..7  (k-block of 8 rows)
  const int n8 = (tid & 31) * 8;       // 0..248 (n-octet)

  v4f acc[8][4] = {};
  v8us bu[8];

  // ---- prologue: tiles 0 and 1 ----
  if (isB) {
#pragma unroll
    for (int r = 0; r < 8; ++r)
      bu[r] = *(const v8us*)((const unsigned short*)Vb +
                             (size_t)(dblk * 8 + r) * HW_DIM + n8);
    bwrite8(smem + 2 * TILE_E, bu, dblk, n8);
#pragma unroll
    for (int r = 0; r < 8; ++r)
      bu[r] = *(const v8us*)((const unsigned short*)Vb +
                             (size_t)(64 + dblk * 8 + r) * HW_DIM + n8);
    bwrite8(smem + 3 * TILE_E, bu, dblk, n8);
  } else {
    stageA8(Ab, smem, 0, ATTN_STRIDE, w4, lrow, lc);
    stageA8(Ab, smem + TILE_E, 64, ATTN_STRIDE, w4, lrow, lc);
  }
  asm volatile("s_waitcnt vmcnt(8)" ::: "memory");
  __builtin_amdgcn_s_barrier();

  v8bf a[4][2], b01[2][2], b23[2][2];
  for (int kt = 0; kt < 8; ++kt) {
    const bf16* LA = smem + (kt & 1) * TILE_E;
    const bf16* LB = smem + (2 + (kt & 1)) * TILE_E;
    bf16* SA = smem + (kt & 1) * TILE_E;
    bf16* SB = smem + (2 + (kt & 1)) * TILE_E;
    // ---- ph0: ds_read a[0-3] + b01; issue B(kt+2) global loads; MFMA q0 ----
#pragma unroll
    for (int mi = 0; mi < 4; ++mi)
#pragma unroll
      for (int kk = 0; kk < 2; ++kk)
        a[mi][kk] = ld_frag8(LA, wm * 128 + mi * 16 + rl, kk * 4 + kq);
#pragma unroll
    for (int ni = 0; ni < 2; ++ni)
#pragma unroll
      for (int kk = 0; kk < 2; ++kk)
        b01[ni][kk] = ld_frag8B(LB, wn * 64 + ni * 16 + rl, kk * 4 + kq);
    if (isB && kt < 6) {
      const int d0 = (kt + 2) * 64 + dblk * 8;
#pragma unroll
      for (int r = 0; r < 8; ++r)
        bu[r] = *(const v8us*)((const unsigned short*)Vb +
                               (size_t)(d0 + r) * HW_DIM + n8);
    }
    __builtin_amdgcn_s_barrier();
    asm volatile("s_waitcnt lgkmcnt(0)");
    __builtin_amdgcn_s_setprio(1);
#pragma unroll
    for (int kk = 0; kk < 2; ++kk)
#pragma unroll
      for (int mi = 0; mi < 4; ++mi)
#pragma unroll
        for (int ni = 0; ni < 2; ++ni)
          acc[mi][ni] = __builtin_amdgcn_mfma_f32_16x16x32_bf16(
              a[mi][kk], b01[ni][kk], acc[mi][ni], 0, 0, 0);
    __builtin_amdgcn_s_setprio(0);
    __builtin_amdgcn_s_barrier();
    // ---- ph1: ds_read b23; MFMA q1  [B buffer fully consumed after this] --
#pragma unroll
    for (int ni = 0; ni < 2; ++ni)
#pragma unroll
      for (int kk = 0; kk < 2; ++kk)
        b23[ni][kk] = ld_frag8B(LB, wn * 64 + (ni + 2) * 16 + rl, kk * 4 + kq);
    __builtin_amdgcn_s_barrier();
    asm volatile("s_waitcnt lgkmcnt(0)");
    __builtin_amdgcn_s_setprio(1);
#pragma unroll
    for (int kk = 0; kk < 2; ++kk)
#pragma unroll
      for (int mi = 0; mi < 4; ++mi)
#pragma unroll
        for (int ni = 0; ni < 2; ++ni)
          acc[mi][ni + 2] = __builtin_amdgcn_mfma_f32_16x16x32_bf16(
              a[mi][kk], b23[ni][kk], acc[mi][ni + 2], 0, 0, 0);
    __builtin_amdgcn_s_setprio(0);
    __builtin_amdgcn_s_barrier();
    // ---- ph2: ds_read a[4-7]; transposed B(kt+2) ds_writes; MFMA q2 -------
#pragma unroll
    for (int mi = 0; mi < 4; ++mi)
#pragma unroll
      for (int kk = 0; kk < 2; ++kk)
        a[mi][kk] = ld_frag8(LA, wm * 128 + (mi + 4) * 16 + rl, kk * 4 + kq);
    if (isB && kt < 6) bwrite8(SB, bu, dblk, n8);
    __builtin_amdgcn_s_barrier();
    asm volatile("s_waitcnt lgkmcnt(0)");
    __builtin_amdgcn_s_setprio(1);
#pragma unroll
    for (int kk = 0; kk < 2; ++kk)
#pragma unroll
      for (int mi = 0; mi < 4; ++mi)
#pragma unroll
        for (int ni = 0; ni < 2; ++ni)
          acc[mi + 4][ni + 2] = __builtin_amdgcn_mfma_f32_16x16x32_bf16(
              a[mi][kk], b23[ni][kk], acc[mi + 4][ni + 2], 0, 0, 0);
    __builtin_amdgcn_s_setprio(0);
    __builtin_amdgcn_s_barrier();
    // ---- ph3: stage A(kt+2) (waves 4-7); MFMA q3; boundary vmcnt ----------
    if (!isB && kt < 6)
      stageA8(Ab, SA, (kt + 2) * 64, ATTN_STRIDE, w4, lrow, lc);
    __builtin_amdgcn_s_barrier();
    __builtin_amdgcn_s_setprio(1);
#pragma unroll
    for (int kk = 0; kk < 2; ++kk)
#pragma unroll
      for (int mi = 0; mi < 4; ++mi)
#pragma unroll
        for (int ni = 0; ni < 2; ++ni)
          acc[mi + 4][ni] = __builtin_amdgcn_mfma_f32_16x16x32_bf16(
              a[mi][kk], b01[ni][kk], acc[mi + 4][ni], 0, 0, 0);
    __builtin_amdgcn_s_setprio(0);
    if (kt < 6)
      asm volatile("s_waitcnt vmcnt(8)" ::: "memory");   // A(kt+1) landed
    else if (kt == 6)
      asm volatile("s_waitcnt vmcnt(0)" ::: "memory");   // A(7) landed
    __builtin_amdgcn_s_barrier();
  }

  float* ob = out + (size_t)b * ((size_t)C_DIM * HW_DIM) +
              (size_t)(cb * 256) * HW_DIM + nb * 256;
  epilogue_bounce(acc, smem, ob, HW_DIM, wave, lane);
}

// ---------------- pass 4: LN over HW=4096, fused gamma*av + v residual ------
__global__ __launch_bounds__(256) void k_ln(
    float* __restrict__ out, const unsigned short* __restrict__ vres,
    const float* __restrict__ gamma, const float* __restrict__ w,
    const float* __restrict__ bias) {
  const int row = blockIdx.x;  // 0..8191
  float* p = out + (size_t)row * HW_DIM;
  const unsigned short* vr = vres + (size_t)row * HW_DIM;
  const float g = gamma[0];
  const int tid = threadIdx.x;
  float4 vals[4];
  float s = 0.f, ss = 0.f;
#pragma unroll
  for (int i = 0; i < 4; ++i) {
    const int idx = tid + i * 256;
    const float4 av = ((const float4*)p)[idx];
    const v4us rv = *(const v4us*)(vr + idx * 4);
    float4 vv;
    vv.x = g * av.x + bf2f(rv[0]);
    vv.y = g * av.y + bf2f(rv[1]);
    vv.z = g * av.z + bf2f(rv[2]);
    vv.w = g * av.w + bf2f(rv[3]);
    vals[i] = vv;
    s += vv.x + vv.y + vv.z + vv.w;
    ss += vv.x * vv.x + vv.y * vv.y + vv.z * vv.z + vv.w * vv.w;
  }
#pragma unroll
  for (int off = 32; off > 0; off >>= 1) {
    s += __shfl_xor(s, off);
    ss += __shfl_xor(ss, off);
  }
  __shared__ float rs[4], rss[4];
  const int wv = tid >> 6, ln = tid & 63;
  if (ln == 0) { rs[wv] = s; rss[wv] = ss; }
  __syncthreads();
  s = rs[0] + rs[1] + rs[2] + rs[3];
  ss = rss[0] + rss[1] + rss[2] + rss[3];
  const float mean = s * (1.f / HW_DIM);
  const float var = ss * (1.f / HW_DIM) - mean * mean;
  const float rstd = rsqrtf(var + LN_EPS);
#pragma unroll
  for (int i = 0; i < 4; ++i) {
    const int idx = tid + i * 256;
    const float4 vv = vals[i];
    const float4 w4 = ((const float4*)w)[idx];
    const float4 b4 = ((const float4*)bias)[idx];
    float4 r;
    r.x = (vv.x - mean) * rstd * w4.x + b4.x;
    r.y = (vv.y - mean) * rstd * w4.y + b4.y;
    r.z = (vv.z - mean) * rstd * w4.z + b4.z;
    r.w = (vv.w - mean) * rstd * w4.w + b4.w;
    ((float4*)p)[idx] = r;
  }
}

extern "C" void kernel_launch(void* const* d_in, const int* in_sizes, int n_in,
                              void* d_out, int out_size, void* d_ws, size_t ws_size,
                              hipStream_t stream) {
  const float* x = (const float*)d_in[0];
  const float* gamma = (const float*)d_in[1];
  const float* lnw = (const float*)d_in[2];
  const float* lnb = (const float*)d_in[3];
  float* out = (float*)d_out;
  char* ws = (char*)d_ws;

  const size_t n_elem = (size_t)B_DIM * C_DIM * HW_DIM;       // 33,554,432
  unsigned short* vbf = (unsigned short*)ws;                  // 64 MiB
  float* e_part = (float*)(ws + 4 * n_elem);                  // 4 x 16.8 MiB
  unsigned short* attn = (unsigned short*)e_part;             // aliased

  k_convert<<<2048, 256, 0, stream>>>(x, vbf);
  k_gemm1<<<256, 512, 0, stream>>>((const bf16*)vbf, e_part);
  k_softmax<<<B_DIM * C_DIM, 256, 0, stream>>>(e_part, attn);
  k_gemm2<<<512, 512, 0, stream>>>((const bf16*)attn, (const bf16*)vbf, out);
  k_ln<<<B_DIM * C_DIM, 256, 0, stream>>>(out, vbf, gamma, lnw, lnb);
}

// Round 9
// 214.962 us; speedup vs baseline: 1.1322x; 1.1322x over previous
//
#include <hip/hip_runtime.h>
#include <hip/hip_bf16.h>

#define B_DIM 16
#define C_DIM 512
#define HW_DIM 4096
#define LN_EPS 1e-5f

using bf16 = __hip_bfloat16;
typedef __bf16 v8bf __attribute__((ext_vector_type(8)));
typedef float v4f __attribute__((ext_vector_type(4)));
typedef unsigned short v8us __attribute__((ext_vector_type(8)));
typedef unsigned short v4us __attribute__((ext_vector_type(4)));
using gptr_t = const __attribute__((address_space(1))) void*;
using lptr_t = __attribute__((address_space(3))) void*;

__device__ __forceinline__ unsigned short f2bf(float f) {
  unsigned int u = __float_as_uint(f);
  u = (u + 0x7fffu + ((u >> 16) & 1u)) >> 16;  // RNE
  return (unsigned short)u;
}
__device__ __forceinline__ float bf2f(unsigned short us) {
  return __uint_as_float(((unsigned int)us) << 16);
}

// ---------------- pass 0: f32 -> bf16 (V) and bf16 transposed (VT) ----------
// Round-5 measured config (swizzled [64][64] LDS, 0 bank conflicts).
__global__ __launch_bounds__(256) void k_convert_transpose(
    const float* __restrict__ x, unsigned short* __restrict__ v,
    unsigned short* __restrict__ vt) {
  __shared__ unsigned short tile[64 * 64];  // 8 KiB
  const int tid = threadIdx.x;
  const int b = blockIdx.z;
  const int n0 = blockIdx.x * 64;
  const int c0 = blockIdx.y * 64;
  const size_t boff = (size_t)b * ((size_t)C_DIM * HW_DIM);
  const float* xb = x + boff;
  unsigned short* vb = v + boff;
  unsigned short* vtb = vt + boff;

  const int cl = tid >> 3;           // 0..31
  const int hb = tid & 7;            // block index along hw
  const int h8 = hb * 8;             // 0,8,..56
#pragma unroll
  for (int j = 0; j < 2; ++j) {
    const int c = cl + j * 32;
    const float* src = xb + (size_t)(c0 + c) * HW_DIM + n0 + h8;
    const float4 f0 = ((const float4*)src)[0];
    const float4 f1 = ((const float4*)src)[1];
    v8us pack;
    pack[0] = f2bf(f0.x); pack[1] = f2bf(f0.y);
    pack[2] = f2bf(f0.z); pack[3] = f2bf(f0.w);
    pack[4] = f2bf(f1.x); pack[5] = f2bf(f1.y);
    pack[6] = f2bf(f1.z); pack[7] = f2bf(f1.w);
    *(v8us*)(vb + (size_t)(c0 + c) * HW_DIM + n0 + h8) = pack;
    const int key = (c & 7) ^ ((c >> 3) & 7);
    *(v8us*)(tile + c * 64 + ((hb ^ key) << 3)) = pack;  // 16B aligned
  }
  __syncthreads();
  const int nl = tid >> 3;           // 0..31 -> handles VT rows 2nl, 2nl+1
  const int c8 = (tid & 7) * 8;      // 0,8,..56
  const int n = 2 * nl;
  v8us pa, pb;
#pragma unroll
  for (int e = 0; e < 8; ++e) {
    const int r = c8 + e;
    const int key = (r & 7) ^ ((r >> 3) & 7);
    const unsigned int w = *(const unsigned int*)(
        tile + r * 64 + (((n >> 3) ^ key) << 3) + (n & 7));
    pa[e] = (unsigned short)(w & 0xffffu);
    pb[e] = (unsigned short)(w >> 16);
  }
  *(v8us*)(vtb + (size_t)(n0 + n) * C_DIM + c0 + c8) = pa;
  *(v8us*)(vtb + (size_t)(n0 + n + 1) * C_DIM + c0 + c8) = pb;
}

// ---------------- gemm1 pieces (dbuf 128x128, round-5 measured) -------------
__device__ __forceinline__ void stage_tiles(
    const bf16* __restrict__ a_base, const bf16* __restrict__ b_base,
    const int stride, const int k0, const int wave, const int lane,
    bf16* ldsA, bf16* ldsB) {
  const int srow = lane >> 3;        // 0..7
  const int skcol = (lane & 7) * 8;  // 0..56
#pragma unroll
  for (int i = 0; i < 4; ++i) {
    const int ci = wave * 4 + i;     // chunk of 8 rows
    const int row = ci * 8 + srow;
    __builtin_amdgcn_global_load_lds(
        (gptr_t)(a_base + (size_t)row * stride + k0 + skcol),
        (lptr_t)(ldsA + ci * 512), 16, 0, 0);
    __builtin_amdgcn_global_load_lds(
        (gptr_t)(b_base + (size_t)row * stride + k0 + skcol),
        (lptr_t)(ldsB + ci * 512), 16, 0, 0);
  }
}

__device__ __forceinline__ void compute_tile(
    const bf16* ldsA, const bf16* ldsB, const int wave, const int lane,
    v4f acc[4][4]) {
  const int kb = (lane >> 4) * 8;
  const int rl = lane & 15;
  const int wr = wave >> 1, wc = wave & 1;
#pragma unroll
  for (int kk = 0; kk < 2; ++kk) {
    v8bf af[4], bfr[4];
#pragma unroll
    for (int m = 0; m < 4; ++m)
      af[m] = *(const v8bf*)(ldsA + (wr * 64 + m * 16 + rl) * 64 + kk * 32 + kb);
#pragma unroll
    for (int n = 0; n < 4; ++n)
      bfr[n] = *(const v8bf*)(ldsB + (wc * 64 + n * 16 + rl) * 64 + kk * 32 + kb);
#pragma unroll
    for (int m = 0; m < 4; ++m)
#pragma unroll
      for (int n = 0; n < 4; ++n)
        acc[m][n] = __builtin_amdgcn_mfma_f32_16x16x32_bf16(af[m], bfr[n], acc[m][n], 0, 0, 0);
  }
}

__device__ __forceinline__ void gemm_dbuf_loop(
    const bf16* __restrict__ a_base, const bf16* __restrict__ b_base,
    const int stride, const int ksteps, const int wave, const int lane,
    bf16* ldsA0, bf16* ldsB0, bf16* ldsA1, bf16* ldsB1, v4f acc[4][4]) {
  stage_tiles(a_base, b_base, stride, 0, wave, lane, ldsA0, ldsB0);
  __syncthreads();
  int cur = 0;
  for (int kt = 0; kt < ksteps - 1; ++kt) {
    if (cur == 0)
      stage_tiles(a_base, b_base, stride, (kt + 1) * 64, wave, lane, ldsA1, ldsB1);
    else
      stage_tiles(a_base, b_base, stride, (kt + 1) * 64, wave, lane, ldsA0, ldsB0);
    compute_tile(cur == 0 ? ldsA0 : ldsA1, cur == 0 ? ldsB0 : ldsB1, wave, lane, acc);
    __syncthreads();
    cur ^= 1;
  }
  compute_tile(cur == 0 ? ldsA0 : ldsA1, cur == 0 ? ldsB0 : ldsB1, wave, lane, acc);
}

// ---------------- pass 1: energy = V V^T (split-K = 2, f32 partials) --------
__global__ __launch_bounds__(256) void k_gemm1(
    const bf16* __restrict__ v, float* __restrict__ e_part) {
  __shared__ __align__(16) bf16 lds[4][128 * 64];  // A0,B0,A1,B1
  int t = blockIdx.x;
  const int ks = t >> 8;
  t &= 255;
  const int b = t >> 4;
  const int cb = (t >> 2) & 3;
  const int db = t & 3;
  const int tid = threadIdx.x;
  const int wave = tid >> 6, lane = tid & 63;
  const bf16* vb = v + (size_t)b * ((size_t)C_DIM * HW_DIM) + ks * (HW_DIM / 2);
  v4f acc[4][4] = {};
  gemm_dbuf_loop(vb + (size_t)(cb * 128) * HW_DIM,
                 vb + (size_t)(db * 128) * HW_DIM,
                 HW_DIM, (HW_DIM / 2) / 64, wave, lane,
                 lds[0], lds[1], lds[2], lds[3], acc);
  float* eb = e_part + (size_t)ks * ((size_t)B_DIM * C_DIM * C_DIM) +
              (size_t)b * (C_DIM * C_DIM);
  const int wr = wave >> 1, wc = wave & 1;
  const int rl = lane & 15;
  const int r0 = (lane >> 4) * 4;
#pragma unroll
  for (int m = 0; m < 4; ++m)
#pragma unroll
    for (int n = 0; n < 4; ++n) {
      const int row0 = cb * 128 + wr * 64 + m * 16 + r0;
      const int col = db * 128 + wc * 64 + n * 16 + rl;
#pragma unroll
      for (int r = 0; r < 4; ++r)
        eb[(size_t)(row0 + r) * C_DIM + col] = acc[m][n][r];
    }
}

// ---------------- pass 2: row softmax (sums 2 partials), write bf16 ---------
__global__ __launch_bounds__(256) void k_softmax(
    const float* __restrict__ e_part, unsigned short* __restrict__ attn) {
  const int row = blockIdx.x;  // 0..8191 = b*512 + c
  const float* e0 = e_part + (size_t)row * C_DIM;
  const float* e1 = e0 + (size_t)B_DIM * C_DIM * C_DIM;
  const int tid = threadIdx.x;
  const float v0 = e0[tid] + e1[tid];
  const float v1 = e0[tid + 256] + e1[tid + 256];
  float mx = fmaxf(v0, v1);
#pragma unroll
  for (int off = 32; off > 0; off >>= 1) mx = fmaxf(mx, __shfl_xor(mx, off));
  __shared__ float rmax[4], rsum[4];
  const int wv = tid >> 6, ln = tid & 63;
  if (ln == 0) rmax[wv] = mx;
  __syncthreads();
  mx = fmaxf(fmaxf(rmax[0], rmax[1]), fmaxf(rmax[2], rmax[3]));
  const float p0 = __expf(v0 - mx), p1 = __expf(v1 - mx);
  float s = p0 + p1;
#pragma unroll
  for (int off = 32; off > 0; off >>= 1) s += __shfl_xor(s, off);
  if (ln == 0) rsum[wv] = s;
  __syncthreads();
  s = rsum[0] + rsum[1] + rsum[2] + rsum[3];
  const float inv = 1.0f / s;
  attn[(size_t)row * C_DIM + tid] = f2bf(p0 * inv);
  attn[(size_t)row * C_DIM + tid + 256] = f2bf(p1 * inv);
}

// ---------------- pass 3: 256x256-tile 8-wave 8-phase GEMM ------------------
// av = attn @ V written as BF16 (halves gemm2 writes + LN reads).
#define TILE_E (256 * 64)

__device__ __forceinline__ void stage_half8(
    const bf16* __restrict__ g, bf16* l, int k0, int wave, int lane) {
  const int lrow = lane >> 3, lc = lane & 7;
#pragma unroll
  for (int i = 0; i < 2; ++i) {
    const int row = i * 64 + wave * 8 + lrow;
    __builtin_amdgcn_global_load_lds(
        (gptr_t)(g + (size_t)row * C_DIM + k0 + ((lc ^ (row & 7)) << 3)),
        (lptr_t)(l + (i * 64 + wave * 8) * 64), 16, 0, 0);
  }
}
__device__ __forceinline__ void stage_op2(
    const bf16* __restrict__ g, bf16* l, int k0, int wave, int lane) {
  stage_half8(g, l, k0, wave, lane);
  stage_half8(g + (size_t)128 * C_DIM, l + 128 * 64, k0, wave, lane);
}
__device__ __forceinline__ v8bf ld_frag8(const bf16* l, int row, int j) {
  return *(const v8bf*)(l + row * 64 + ((j ^ (row & 7)) << 3));
}

__global__ __launch_bounds__(512, 2) void k_gemm2(
    const bf16* __restrict__ attn, const bf16* __restrict__ vt,
    unsigned short* __restrict__ av) {
  __shared__ __align__(16) bf16 smem[4 * TILE_E];  // 128 KiB total
  const int bid = blockIdx.x;
  // XCD-chunked bijective swizzle (512 % 8 == 0)
  const int t = (bid & 7) * 64 + (bid >> 3);
  const int b = t >> 5;
  const int cb = (t >> 4) & 1;
  const int nb = t & 15;
  const int tid = threadIdx.x;
  const int wave = tid >> 6, lane = tid & 63;
  const int wm = wave >> 2, wn = wave & 3;  // 2M x 4N waves, 128x64 each
  const int rl = lane & 15, kq = lane >> 4;

  const bf16* Ab = attn + (size_t)b * (C_DIM * C_DIM) + (size_t)(cb * 256) * C_DIM;
  const bf16* Bb = vt + (size_t)b * ((size_t)C_DIM * HW_DIM) + (size_t)(nb * 256) * C_DIM;

  v4f acc[8][4] = {};

  // prologue: stage tiles 0 and 1 fully (order per tile: B then A)
  stage_op2(Bb, smem + 2 * TILE_E, 0, wave, lane);
  stage_op2(Ab, smem, 0, wave, lane);
  stage_op2(Bb, smem + 3 * TILE_E, 64, wave, lane);
  stage_op2(Ab, smem + TILE_E, 64, wave, lane);
  asm volatile("s_waitcnt vmcnt(8)" ::: "memory");  // tile 0 landed
  __builtin_amdgcn_s_barrier();

  v8bf a[4][2], b01[2][2], b23[2][2];
  for (int kt = 0; kt < 8; ++kt) {
    const bf16* LA = smem + (kt & 1) * TILE_E;
    const bf16* LB = smem + (2 + (kt & 1)) * TILE_E;
    bf16* SA = smem + (kt & 1) * TILE_E;
    bf16* SB = smem + (2 + (kt & 1)) * TILE_E;
    // ---- ph0: read A m0-3 + B n0-1; MFMA q0 ----
#pragma unroll
    for (int mi = 0; mi < 4; ++mi)
#pragma unroll
      for (int kk = 0; kk < 2; ++kk)
        a[mi][kk] = ld_frag8(LA, wm * 128 + mi * 16 + rl, kk * 4 + kq);
#pragma unroll
    for (int ni = 0; ni < 2; ++ni)
#pragma unroll
      for (int kk = 0; kk < 2; ++kk)
        b01[ni][kk] = ld_frag8(LB, wn * 64 + ni * 16 + rl, kk * 4 + kq);
    __builtin_amdgcn_s_barrier();
    asm volatile("s_waitcnt lgkmcnt(0)");
    __builtin_amdgcn_s_setprio(1);
#pragma unroll
    for (int kk = 0; kk < 2; ++kk)
#pragma unroll
      for (int mi = 0; mi < 4; ++mi)
#pragma unroll
        for (int ni = 0; ni < 2; ++ni)
          acc[mi][ni] = __builtin_amdgcn_mfma_f32_16x16x32_bf16(
              a[mi][kk], b01[ni][kk], acc[mi][ni], 0, 0, 0);
    __builtin_amdgcn_s_setprio(0);
    __builtin_amdgcn_s_barrier();
    // ---- ph1: read B n2-3; MFMA q1 ----
#pragma unroll
    for (int ni = 0; ni < 2; ++ni)
#pragma unroll
      for (int kk = 0; kk < 2; ++kk)
        b23[ni][kk] = ld_frag8(LB, wn * 64 + (ni + 2) * 16 + rl, kk * 4 + kq);
    __builtin_amdgcn_s_barrier();
    asm volatile("s_waitcnt lgkmcnt(0)");
    __builtin_amdgcn_s_setprio(1);
#pragma unroll
    for (int kk = 0; kk < 2; ++kk)
#pragma unroll
      for (int mi = 0; mi < 4; ++mi)
#pragma unroll
        for (int ni = 0; ni < 2; ++ni)
          acc[mi][ni + 2] = __builtin_amdgcn_mfma_f32_16x16x32_bf16(
              a[mi][kk], b23[ni][kk], acc[mi][ni + 2], 0, 0, 0);
    __builtin_amdgcn_s_setprio(0);
    __builtin_amdgcn_s_barrier();
    // ---- ph2: read A m4-7; stage B(kt+2); MFMA q2 ----
#pragma unroll
    for (int mi = 0; mi < 4; ++mi)
#pragma unroll
      for (int kk = 0; kk < 2; ++kk)
        a[mi][kk] = ld_frag8(LA, wm * 128 + (mi + 4) * 16 + rl, kk * 4 + kq);
    if (kt < 6) stage_op2(Bb, SB, (kt + 2) * 64, wave, lane);
    __builtin_amdgcn_s_barrier();
    asm volatile("s_waitcnt lgkmcnt(0)");
    __builtin_amdgcn_s_setprio(1);
#pragma unroll
    for (int kk = 0; kk < 2; ++kk)
#pragma unroll
      for (int mi = 0; mi < 4; ++mi)
#pragma unroll
        for (int ni = 0; ni < 2; ++ni)
          acc[mi + 4][ni + 2] = __builtin_amdgcn_mfma_f32_16x16x32_bf16(
              a[mi][kk], b23[ni][kk], acc[mi + 4][ni + 2], 0, 0, 0);
    __builtin_amdgcn_s_setprio(0);
    __builtin_amdgcn_s_barrier();
    // ---- ph3: stage A(kt+2); MFMA q3; counted vmcnt at K-tile boundary ----
    if (kt < 6) stage_op2(Ab, SA, (kt + 2) * 64, wave, lane);
    __builtin_amdgcn_s_barrier();
    __builtin_amdgcn_s_setprio(1);
#pragma unroll
    for (int kk = 0; kk < 2; ++kk)
#pragma unroll
      for (int mi = 0; mi < 4; ++mi)
#pragma unroll
        for (int ni = 0; ni < 2; ++ni)
          acc[mi + 4][ni] = __builtin_amdgcn_mfma_f32_16x16x32_bf16(
              a[mi][kk], b01[ni][kk], acc[mi + 4][ni], 0, 0, 0);
    __builtin_amdgcn_s_setprio(0);
    if (kt < 6)
      asm volatile("s_waitcnt vmcnt(8)" ::: "memory");   // tile kt+1 landed
    else if (kt == 6)
      asm volatile("s_waitcnt vmcnt(0)" ::: "memory");   // tile 7 landed
    __builtin_amdgcn_s_barrier();
  }

  // ---- epilogue: acc -> swizzled LDS (f32) -> coalesced BF16 row stores ----
  // LDS viewed as [128][256] f32; 16B blocks XOR-swizzled by row&7.
  // Store side: each lane packs 4 f32 -> 4 bf16 (8B); wave covers a full
  // 256-elem row (512B contiguous).
  float* smf = (float*)smem;
  unsigned short* ob = av + (size_t)b * ((size_t)C_DIM * HW_DIM) +
                       (size_t)(cb * 256) * HW_DIM + nb * 256;
#pragma unroll
  for (int h = 0; h < 2; ++h) {
    if (wm == h) {
#pragma unroll
      for (int mi = 0; mi < 8; ++mi)
#pragma unroll
        for (int ni = 0; ni < 4; ++ni)
#pragma unroll
          for (int rr = 0; rr < 4; ++rr) {
            const int rloc = mi * 16 + kq * 4 + rr;  // 0..127
            const int col = wn * 64 + ni * 16 + rl;
            const int key = rloc & 7;
            smf[rloc * 256 + ((((col >> 2) ^ key) << 2) | (col & 3))] =
                acc[mi][ni][rr];
          }
    }
    __syncthreads();
#pragma unroll
    for (int it = 0; it < 16; ++it) {
      const int rloc = it * 8 + wave;
      const float4 vv =
          *(const float4*)(smf + rloc * 256 + ((lane ^ (rloc & 7)) << 2));
      v4us p;
      p[0] = f2bf(vv.x); p[1] = f2bf(vv.y);
      p[2] = f2bf(vv.z); p[3] = f2bf(vv.w);
      *(v4us*)(ob + (size_t)(h * 128 + rloc) * HW_DIM + lane * 4) = p;
    }
    __syncthreads();
  }
}

// ---------------- pass 4: LN over HW=4096, av bf16 + residual bf16 ----------
__global__ __launch_bounds__(256) void k_ln(
    float* __restrict__ out, const unsigned short* __restrict__ av,
    const unsigned short* __restrict__ vres,
    const float* __restrict__ gamma, const float* __restrict__ w,
    const float* __restrict__ bias) {
  const int row = blockIdx.x;  // 0..8191
  float* p = out + (size_t)row * HW_DIM;
  const unsigned short* ap = av + (size_t)row * HW_DIM;
  const unsigned short* vr = vres + (size_t)row * HW_DIM;
  const float g = gamma[0];
  const int tid = threadIdx.x;
  float4 vals[4];
  float s = 0.f, ss = 0.f;
#pragma unroll
  for (int i = 0; i < 4; ++i) {
    const int idx = tid + i * 256;
    const v4us au = *(const v4us*)(ap + idx * 4);
    const v4us rv = *(const v4us*)(vr + idx * 4);
    float4 vv;
    vv.x = g * bf2f(au[0]) + bf2f(rv[0]);
    vv.y = g * bf2f(au[1]) + bf2f(rv[1]);
    vv.z = g * bf2f(au[2]) + bf2f(rv[2]);
    vv.w = g * bf2f(au[3]) + bf2f(rv[3]);
    vals[i] = vv;
    s += vv.x + vv.y + vv.z + vv.w;
    ss += vv.x * vv.x + vv.y * vv.y + vv.z * vv.z + vv.w * vv.w;
  }
#pragma unroll
  for (int off = 32; off > 0; off >>= 1) {
    s += __shfl_xor(s, off);
    ss += __shfl_xor(ss, off);
  }
  __shared__ float rs[4], rss[4];
  const int wv = tid >> 6, ln = tid & 63;
  if (ln == 0) { rs[wv] = s; rss[wv] = ss; }
  __syncthreads();
  s = rs[0] + rs[1] + rs[2] + rs[3];
  ss = rss[0] + rss[1] + rss[2] + rss[3];
  const float mean = s * (1.f / HW_DIM);
  const float var = ss * (1.f / HW_DIM) - mean * mean;
  const float rstd = rsqrtf(var + LN_EPS);
#pragma unroll
  for (int i = 0; i < 4; ++i) {
    const int idx = tid + i * 256;
    const float4 vv = vals[i];
    const float4 w4 = ((const float4*)w)[idx];
    const float4 b4 = ((const float4*)bias)[idx];
    float4 r;
    r.x = (vv.x - mean) * rstd * w4.x + b4.x;
    r.y = (vv.y - mean) * rstd * w4.y + b4.y;
    r.z = (vv.z - mean) * rstd * w4.z + b4.z;
    r.w = (vv.w - mean) * rstd * w4.w + b4.w;
    ((float4*)p)[idx] = r;
  }
}

extern "C" void kernel_launch(void* const* d_in, const int* in_sizes, int n_in,
                              void* d_out, int out_size, void* d_ws, size_t ws_size,
                              hipStream_t stream) {
  const float* x = (const float*)d_in[0];
  const float* gamma = (const float*)d_in[1];
  const float* lnw = (const float*)d_in[2];
  const float* lnb = (const float*)d_in[3];
  float* out = (float*)d_out;
  char* ws = (char*)d_ws;

  const size_t n_elem = (size_t)B_DIM * C_DIM * HW_DIM;       // 33,554,432
  const size_t e_elems = (size_t)B_DIM * C_DIM * C_DIM;       // 4,194,304
  unsigned short* vbf = (unsigned short*)ws;                  // 64 MiB
  unsigned short* vbfT = (unsigned short*)(ws + 2 * n_elem);  // 64 MiB
  float* e_part = (float*)(ws + 4 * n_elem);                  // 2 x 16 MiB
  unsigned short* attn =
      (unsigned short*)(ws + 4 * n_elem + 2 * e_elems * sizeof(float));  // 8 MiB
  unsigned short* av = (unsigned short*)(ws + 4 * n_elem +
                                         2 * e_elems * sizeof(float) +
                                         2 * e_elems);        // 64 MiB

  k_convert_transpose<<<dim3(HW_DIM / 64, C_DIM / 64, B_DIM), 256, 0, stream>>>(
      x, vbf, vbfT);
  k_gemm1<<<512, 256, 0, stream>>>((const bf16*)vbf, e_part);
  k_softmax<<<B_DIM * C_DIM, 256, 0, stream>>>(e_part, attn);
  k_gemm2<<<512, 512, 0, stream>>>((const bf16*)attn, (const bf16*)vbfT, av);
  k_ln<<<B_DIM * C_DIM, 256, 0, stream>>>(out, av, vbf, gamma, lnw, lnb);
}

// Round 10
// 212.357 us; speedup vs baseline: 1.1461x; 1.0123x over previous
//
#include <hip/hip_runtime.h>
#include <hip/hip_bf16.h>

#define B_DIM 16
#define C_DIM 512
#define HW_DIM 4096
#define LN_EPS 1e-5f

using bf16 = __hip_bfloat16;
typedef __bf16 v8bf __attribute__((ext_vector_type(8)));
typedef float v4f __attribute__((ext_vector_type(4)));
typedef unsigned short v8us __attribute__((ext_vector_type(8)));
typedef unsigned short v4us __attribute__((ext_vector_type(4)));
using gptr_t = const __attribute__((address_space(1))) void*;
using lptr_t = __attribute__((address_space(3))) void*;

__device__ __forceinline__ unsigned short f2bf(float f) {
  unsigned int u = __float_as_uint(f);
  u = (u + 0x7fffu + ((u >> 16) & 1u)) >> 16;  // RNE
  return (unsigned short)u;
}
__device__ __forceinline__ float bf2f(unsigned short us) {
  return __uint_as_float(((unsigned int)us) << 16);
}

// ---------------- pass 0: f32 -> bf16 (V) and bf16 transposed (VT) ----------
// Round-5 measured config (swizzled [64][64] LDS, 0 bank conflicts).
__global__ __launch_bounds__(256) void k_convert_transpose(
    const float* __restrict__ x, unsigned short* __restrict__ v,
    unsigned short* __restrict__ vt) {
  __shared__ unsigned short tile[64 * 64];  // 8 KiB
  const int tid = threadIdx.x;
  const int b = blockIdx.z;
  const int n0 = blockIdx.x * 64;
  const int c0 = blockIdx.y * 64;
  const size_t boff = (size_t)b * ((size_t)C_DIM * HW_DIM);
  const float* xb = x + boff;
  unsigned short* vb = v + boff;
  unsigned short* vtb = vt + boff;

  const int cl = tid >> 3;           // 0..31
  const int hb = tid & 7;            // block index along hw
  const int h8 = hb * 8;             // 0,8,..56
#pragma unroll
  for (int j = 0; j < 2; ++j) {
    const int c = cl + j * 32;
    const float* src = xb + (size_t)(c0 + c) * HW_DIM + n0 + h8;
    const float4 f0 = ((const float4*)src)[0];
    const float4 f1 = ((const float4*)src)[1];
    v8us pack;
    pack[0] = f2bf(f0.x); pack[1] = f2bf(f0.y);
    pack[2] = f2bf(f0.z); pack[3] = f2bf(f0.w);
    pack[4] = f2bf(f1.x); pack[5] = f2bf(f1.y);
    pack[6] = f2bf(f1.z); pack[7] = f2bf(f1.w);
    *(v8us*)(vb + (size_t)(c0 + c) * HW_DIM + n0 + h8) = pack;
    const int key = (c & 7) ^ ((c >> 3) & 7);
    *(v8us*)(tile + c * 64 + ((hb ^ key) << 3)) = pack;  // 16B aligned
  }
  __syncthreads();
  const int nl = tid >> 3;           // 0..31 -> handles VT rows 2nl, 2nl+1
  const int c8 = (tid & 7) * 8;      // 0,8,..56
  const int n = 2 * nl;
  v8us pa, pb;
#pragma unroll
  for (int e = 0; e < 8; ++e) {
    const int r = c8 + e;
    const int key = (r & 7) ^ ((r >> 3) & 7);
    const unsigned int w = *(const unsigned int*)(
        tile + r * 64 + (((n >> 3) ^ key) << 3) + (n & 7));
    pa[e] = (unsigned short)(w & 0xffffu);
    pb[e] = (unsigned short)(w >> 16);
  }
  *(v8us*)(vtb + (size_t)(n0 + n) * C_DIM + c0 + c8) = pa;
  *(v8us*)(vtb + (size_t)(n0 + n + 1) * C_DIM + c0 + c8) = pb;
}

// ---------------- shared 256x256 8-phase GEMM pieces ------------------------
#define TILE_E (256 * 64)

// strided stagers (gemm1)
__device__ __forceinline__ void stage_half8s(
    const bf16* __restrict__ g, bf16* l, int k0, int stride, int wave, int lane) {
  const int lrow = lane >> 3, lc = lane & 7;
#pragma unroll
  for (int i = 0; i < 2; ++i) {
    const int row = i * 64 + wave * 8 + lrow;
    __builtin_amdgcn_global_load_lds(
        (gptr_t)(g + (size_t)row * stride + k0 + ((lc ^ (row & 7)) << 3)),
        (lptr_t)(l + (i * 64 + wave * 8) * 64), 16, 0, 0);
  }
}
__device__ __forceinline__ void stage_op2s(
    const bf16* __restrict__ g, bf16* l, int k0, int stride, int wave, int lane) {
  stage_half8s(g, l, k0, stride, wave, lane);
  stage_half8s(g + (size_t)128 * stride, l + 128 * 64, k0, stride, wave, lane);
}
// C_DIM-stride stagers (gemm2, round-9 verbatim)
__device__ __forceinline__ void stage_half8(
    const bf16* __restrict__ g, bf16* l, int k0, int wave, int lane) {
  const int lrow = lane >> 3, lc = lane & 7;
#pragma unroll
  for (int i = 0; i < 2; ++i) {
    const int row = i * 64 + wave * 8 + lrow;
    __builtin_amdgcn_global_load_lds(
        (gptr_t)(g + (size_t)row * C_DIM + k0 + ((lc ^ (row & 7)) << 3)),
        (lptr_t)(l + (i * 64 + wave * 8) * 64), 16, 0, 0);
  }
}
__device__ __forceinline__ void stage_op2(
    const bf16* __restrict__ g, bf16* l, int k0, int wave, int lane) {
  stage_half8(g, l, k0, wave, lane);
  stage_half8(g + (size_t)128 * C_DIM, l + 128 * 64, k0, wave, lane);
}
__device__ __forceinline__ v8bf ld_frag8(const bf16* l, int row, int j) {
  return *(const v8bf*)(l + row * 64 + ((j ^ (row & 7)) << 3));
}

// K-loop: 4 phases per K-step, dbuf, counted vmcnt(8) (never 0 mid-loop).
__device__ __forceinline__ void gemm_8ph_loop(
    const bf16* __restrict__ Ab, const bf16* __restrict__ Bb,
    const int strideA, const int strideB, const int kts,
    bf16* smem, const int wave, const int lane, v4f acc[8][4]) {
  const int wm = wave >> 2, wn = wave & 3;
  const int rl = lane & 15, kq = lane >> 4;

  stage_op2s(Bb, smem + 2 * TILE_E, 0, strideB, wave, lane);
  stage_op2s(Ab, smem, 0, strideA, wave, lane);
  stage_op2s(Bb, smem + 3 * TILE_E, 64, strideB, wave, lane);
  stage_op2s(Ab, smem + TILE_E, 64, strideA, wave, lane);
  asm volatile("s_waitcnt vmcnt(8)" ::: "memory");
  __builtin_amdgcn_s_barrier();

  v8bf a[4][2], b01[2][2], b23[2][2];
  for (int kt = 0; kt < kts; ++kt) {
    const bf16* LA = smem + (kt & 1) * TILE_E;
    const bf16* LB = smem + (2 + (kt & 1)) * TILE_E;
    bf16* SA = smem + (kt & 1) * TILE_E;
    bf16* SB = smem + (2 + (kt & 1)) * TILE_E;
#pragma unroll
    for (int mi = 0; mi < 4; ++mi)
#pragma unroll
      for (int kk = 0; kk < 2; ++kk)
        a[mi][kk] = ld_frag8(LA, wm * 128 + mi * 16 + rl, kk * 4 + kq);
#pragma unroll
    for (int ni = 0; ni < 2; ++ni)
#pragma unroll
      for (int kk = 0; kk < 2; ++kk)
        b01[ni][kk] = ld_frag8(LB, wn * 64 + ni * 16 + rl, kk * 4 + kq);
    __builtin_amdgcn_s_barrier();
    asm volatile("s_waitcnt lgkmcnt(0)");
    __builtin_amdgcn_s_setprio(1);
#pragma unroll
    for (int kk = 0; kk < 2; ++kk)
#pragma unroll
      for (int mi = 0; mi < 4; ++mi)
#pragma unroll
        for (int ni = 0; ni < 2; ++ni)
          acc[mi][ni] = __builtin_amdgcn_mfma_f32_16x16x32_bf16(
              a[mi][kk], b01[ni][kk], acc[mi][ni], 0, 0, 0);
    __builtin_amdgcn_s_setprio(0);
    __builtin_amdgcn_s_barrier();
#pragma unroll
    for (int ni = 0; ni < 2; ++ni)
#pragma unroll
      for (int kk = 0; kk < 2; ++kk)
        b23[ni][kk] = ld_frag8(LB, wn * 64 + (ni + 2) * 16 + rl, kk * 4 + kq);
    __builtin_amdgcn_s_barrier();
    asm volatile("s_waitcnt lgkmcnt(0)");
    __builtin_amdgcn_s_setprio(1);
#pragma unroll
    for (int kk = 0; kk < 2; ++kk)
#pragma unroll
      for (int mi = 0; mi < 4; ++mi)
#pragma unroll
        for (int ni = 0; ni < 2; ++ni)
          acc[mi][ni + 2] = __builtin_amdgcn_mfma_f32_16x16x32_bf16(
              a[mi][kk], b23[ni][kk], acc[mi][ni + 2], 0, 0, 0);
    __builtin_amdgcn_s_setprio(0);
    __builtin_amdgcn_s_barrier();
#pragma unroll
    for (int mi = 0; mi < 4; ++mi)
#pragma unroll
      for (int kk = 0; kk < 2; ++kk)
        a[mi][kk] = ld_frag8(LA, wm * 128 + (mi + 4) * 16 + rl, kk * 4 + kq);
    if (kt < kts - 2) stage_op2s(Bb, SB, (kt + 2) * 64, strideB, wave, lane);
    __builtin_amdgcn_s_barrier();
    asm volatile("s_waitcnt lgkmcnt(0)");
    __builtin_amdgcn_s_setprio(1);
#pragma unroll
    for (int kk = 0; kk < 2; ++kk)
#pragma unroll
      for (int mi = 0; mi < 4; ++mi)
#pragma unroll
        for (int ni = 0; ni < 2; ++ni)
          acc[mi + 4][ni + 2] = __builtin_amdgcn_mfma_f32_16x16x32_bf16(
              a[mi][kk], b23[ni][kk], acc[mi + 4][ni + 2], 0, 0, 0);
    __builtin_amdgcn_s_setprio(0);
    __builtin_amdgcn_s_barrier();
    if (kt < kts - 2) stage_op2s(Ab, SA, (kt + 2) * 64, strideA, wave, lane);
    __builtin_amdgcn_s_barrier();
    __builtin_amdgcn_s_setprio(1);
#pragma unroll
    for (int kk = 0; kk < 2; ++kk)
#pragma unroll
      for (int mi = 0; mi < 4; ++mi)
#pragma unroll
        for (int ni = 0; ni < 2; ++ni)
          acc[mi + 4][ni] = __builtin_amdgcn_mfma_f32_16x16x32_bf16(
              a[mi][kk], b01[ni][kk], acc[mi + 4][ni], 0, 0, 0);
    __builtin_amdgcn_s_setprio(0);
    if (kt < kts - 2)
      asm volatile("s_waitcnt vmcnt(8)" ::: "memory");
    else if (kt == kts - 2)
      asm volatile("s_waitcnt vmcnt(0)" ::: "memory");
    __builtin_amdgcn_s_barrier();
  }
}

// Epilogue: acc -> swizzled LDS -> 1KiB-contiguous f32 row stores.
__device__ __forceinline__ void epilogue_bounce(
    v4f acc[8][4], bf16* smem, float* ob, const int out_stride,
    const int wave, const int lane) {
  const int wm = wave >> 2, wn = wave & 3;
  const int rl = lane & 15, kq = lane >> 4;
  float* smf = (float*)smem;  // [128][256] f32
#pragma unroll
  for (int h = 0; h < 2; ++h) {
    if (wm == h) {
#pragma unroll
      for (int mi = 0; mi < 8; ++mi)
#pragma unroll
        for (int ni = 0; ni < 4; ++ni)
#pragma unroll
          for (int rr = 0; rr < 4; ++rr) {
            const int rloc = mi * 16 + kq * 4 + rr;  // 0..127
            const int col = wn * 64 + ni * 16 + rl;
            const int key = rloc & 7;
            smf[rloc * 256 + ((((col >> 2) ^ key) << 2) | (col & 3))] =
                acc[mi][ni][rr];
          }
    }
    __syncthreads();
#pragma unroll
    for (int it = 0; it < 16; ++it) {
      const int rloc = it * 8 + wave;
      const float4 vv =
          *(const float4*)(smf + rloc * 256 + ((lane ^ (rloc & 7)) << 2));
      *(float4*)(ob + (size_t)(h * 128 + rloc) * out_stride + lane * 4) = vv;
    }
    __syncthreads();
  }
}

// ---------------- pass 1: energy = V V^T, 256^2 8-phase, split-K 4 ----------
// Grid 256 blocks (1/CU): 16 b x 2 cb x 2 db x 4 ks.  K/split = 1024.
// Ran verified in round 7 (passed, absmax 0.03125).
__global__ __launch_bounds__(512, 2) void k_gemm1(
    const bf16* __restrict__ v, float* __restrict__ e_part) {
  __shared__ __align__(16) bf16 smem[4 * TILE_E];  // 128 KiB
  const int bid = blockIdx.x;
  const int t = (bid & 7) * 32 + (bid >> 3);  // bijective XCD swizzle (256%8==0)
  const int ks = t & 3;
  const int db = (t >> 2) & 1;
  const int cb = (t >> 3) & 1;
  const int b = t >> 4;
  const int tid = threadIdx.x;
  const int wave = tid >> 6, lane = tid & 63;

  const bf16* vb = v + (size_t)b * ((size_t)C_DIM * HW_DIM) + ks * 1024;
  const bf16* Ab = vb + (size_t)(cb * 256) * HW_DIM;
  const bf16* Bb = vb + (size_t)(db * 256) * HW_DIM;

  v4f acc[8][4] = {};
  gemm_8ph_loop(Ab, Bb, HW_DIM, HW_DIM, 16, smem, wave, lane, acc);

  float* ob = e_part + (size_t)ks * ((size_t)B_DIM * C_DIM * C_DIM) +
              (size_t)b * (C_DIM * C_DIM) + (size_t)(cb * 256) * C_DIM + db * 256;
  epilogue_bounce(acc, smem, ob, C_DIM, wave, lane);
}

// ---------------- pass 2: row softmax (sums 4 partials), write bf16 ---------
// attn is a dedicated dense buffer (C_DIM stride) — NO aliasing with e_part.
__global__ __launch_bounds__(256) void k_softmax(
    const float* __restrict__ e_part, unsigned short* __restrict__ attn) {
  const int row = blockIdx.x;  // 0..8191 = b*512 + c
  const size_t bcc = (size_t)B_DIM * C_DIM * C_DIM;
  const float* e0 = e_part + (size_t)row * C_DIM;
  const int tid = threadIdx.x;
  float v0 = 0.f, v1 = 0.f;
#pragma unroll
  for (int p = 0; p < 4; ++p) {
    v0 += e0[p * bcc + tid];
    v1 += e0[p * bcc + tid + 256];
  }
  float mx = fmaxf(v0, v1);
#pragma unroll
  for (int off = 32; off > 0; off >>= 1) mx = fmaxf(mx, __shfl_xor(mx, off));
  __shared__ float rmax[4], rsum[4];
  const int wv = tid >> 6, ln = tid & 63;
  if (ln == 0) rmax[wv] = mx;
  __syncthreads();
  mx = fmaxf(fmaxf(rmax[0], rmax[1]), fmaxf(rmax[2], rmax[3]));
  const float p0 = __expf(v0 - mx), p1 = __expf(v1 - mx);
  float s = p0 + p1;
#pragma unroll
  for (int off = 32; off > 0; off >>= 1) s += __shfl_xor(s, off);
  if (ln == 0) rsum[wv] = s;
  __syncthreads();
  s = rsum[0] + rsum[1] + rsum[2] + rsum[3];
  const float inv = 1.0f / s;
  attn[(size_t)row * C_DIM + tid] = f2bf(p0 * inv);
  attn[(size_t)row * C_DIM + tid + 256] = f2bf(p1 * inv);
}

// ---------------- pass 3: 256x256-tile 8-wave 8-phase GEMM ------------------
// av = attn @ V written as BF16 (round-9 verified).
__global__ __launch_bounds__(512, 2) void k_gemm2(
    const bf16* __restrict__ attn, const bf16* __restrict__ vt,
    unsigned short* __restrict__ av) {
  __shared__ __align__(16) bf16 smem[4 * TILE_E];  // 128 KiB total
  const int bid = blockIdx.x;
  // XCD-chunked bijective swizzle (512 % 8 == 0)
  const int t = (bid & 7) * 64 + (bid >> 3);
  const int b = t >> 5;
  const int cb = (t >> 4) & 1;
  const int nb = t & 15;
  const int tid = threadIdx.x;
  const int wave = tid >> 6, lane = tid & 63;
  const int wm = wave >> 2, wn = wave & 3;  // 2M x 4N waves, 128x64 each
  const int rl = lane & 15, kq = lane >> 4;

  const bf16* Ab = attn + (size_t)b * (C_DIM * C_DIM) + (size_t)(cb * 256) * C_DIM;
  const bf16* Bb = vt + (size_t)b * ((size_t)C_DIM * HW_DIM) + (size_t)(nb * 256) * C_DIM;

  v4f acc[8][4] = {};

  // prologue: stage tiles 0 and 1 fully (order per tile: B then A)
  stage_op2(Bb, smem + 2 * TILE_E, 0, wave, lane);
  stage_op2(Ab, smem, 0, wave, lane);
  stage_op2(Bb, smem + 3 * TILE_E, 64, wave, lane);
  stage_op2(Ab, smem + TILE_E, 64, wave, lane);
  asm volatile("s_waitcnt vmcnt(8)" ::: "memory");  // tile 0 landed
  __builtin_amdgcn_s_barrier();

  v8bf a[4][2], b01[2][2], b23[2][2];
  for (int kt = 0; kt < 8; ++kt) {
    const bf16* LA = smem + (kt & 1) * TILE_E;
    const bf16* LB = smem + (2 + (kt & 1)) * TILE_E;
    bf16* SA = smem + (kt & 1) * TILE_E;
    bf16* SB = smem + (2 + (kt & 1)) * TILE_E;
    // ---- ph0: read A m0-3 + B n0-1; MFMA q0 ----
#pragma unroll
    for (int mi = 0; mi < 4; ++mi)
#pragma unroll
      for (int kk = 0; kk < 2; ++kk)
        a[mi][kk] = ld_frag8(LA, wm * 128 + mi * 16 + rl, kk * 4 + kq);
#pragma unroll
    for (int ni = 0; ni < 2; ++ni)
#pragma unroll
      for (int kk = 0; kk < 2; ++kk)
        b01[ni][kk] = ld_frag8(LB, wn * 64 + ni * 16 + rl, kk * 4 + kq);
    __builtin_amdgcn_s_barrier();
    asm volatile("s_waitcnt lgkmcnt(0)");
    __builtin_amdgcn_s_setprio(1);
#pragma unroll
    for (int kk = 0; kk < 2; ++kk)
#pragma unroll
      for (int mi = 0; mi < 4; ++mi)
#pragma unroll
        for (int ni = 0; ni < 2; ++ni)
          acc[mi][ni] = __builtin_amdgcn_mfma_f32_16x16x32_bf16(
              a[mi][kk], b01[ni][kk], acc[mi][ni], 0, 0, 0);
    __builtin_amdgcn_s_setprio(0);
    __builtin_amdgcn_s_barrier();
    // ---- ph1: read B n2-3; MFMA q1 ----
#pragma unroll
    for (int ni = 0; ni < 2; ++ni)
#pragma unroll
      for (int kk = 0; kk < 2; ++kk)
        b23[ni][kk] = ld_frag8(LB, wn * 64 + (ni + 2) * 16 + rl, kk * 4 + kq);
    __builtin_amdgcn_s_barrier();
    asm volatile("s_waitcnt lgkmcnt(0)");
    __builtin_amdgcn_s_setprio(1);
#pragma unroll
    for (int kk = 0; kk < 2; ++kk)
#pragma unroll
      for (int mi = 0; mi < 4; ++mi)
#pragma unroll
        for (int ni = 0; ni < 2; ++ni)
          acc[mi][ni + 2] = __builtin_amdgcn_mfma_f32_16x16x32_bf16(
              a[mi][kk], b23[ni][kk], acc[mi][ni + 2], 0, 0, 0);
    __builtin_amdgcn_s_setprio(0);
    __builtin_amdgcn_s_barrier();
    // ---- ph2: read A m4-7; stage B(kt+2); MFMA q2 ----
#pragma unroll
    for (int mi = 0; mi < 4; ++mi)
#pragma unroll
      for (int kk = 0; kk < 2; ++kk)
        a[mi][kk] = ld_frag8(LA, wm * 128 + (mi + 4) * 16 + rl, kk * 4 + kq);
    if (kt < 6) stage_op2(Bb, SB, (kt + 2) * 64, wave, lane);
    __builtin_amdgcn_s_barrier();
    asm volatile("s_waitcnt lgkmcnt(0)");
    __builtin_amdgcn_s_setprio(1);
#pragma unroll
    for (int kk = 0; kk < 2; ++kk)
#pragma unroll
      for (int mi = 0; mi < 4; ++mi)
#pragma unroll
        for (int ni = 0; ni < 2; ++ni)
          acc[mi + 4][ni + 2] = __builtin_amdgcn_mfma_f32_16x16x32_bf16(
              a[mi][kk], b23[ni][kk], acc[mi + 4][ni + 2], 0, 0, 0);
    __builtin_amdgcn_s_setprio(0);
    __builtin_amdgcn_s_barrier();
    // ---- ph3: stage A(kt+2); MFMA q3; counted vmcnt at K-tile boundary ----
    if (kt < 6) stage_op2(Ab, SA, (kt + 2) * 64, wave, lane);
    __builtin_amdgcn_s_barrier();
    __builtin_amdgcn_s_setprio(1);
#pragma unroll
    for (int kk = 0; kk < 2; ++kk)
#pragma unroll
      for (int mi = 0; mi < 4; ++mi)
#pragma unroll
        for (int ni = 0; ni < 2; ++ni)
          acc[mi + 4][ni] = __builtin_amdgcn_mfma_f32_16x16x32_bf16(
              a[mi][kk], b01[ni][kk], acc[mi + 4][ni], 0, 0, 0);
    __builtin_amdgcn_s_setprio(0);
    if (kt < 6)
      asm volatile("s_waitcnt vmcnt(8)" ::: "memory");   // tile kt+1 landed
    else if (kt == 6)
      asm volatile("s_waitcnt vmcnt(0)" ::: "memory");   // tile 7 landed
    __builtin_amdgcn_s_barrier();
  }

  // ---- epilogue: acc -> swizzled LDS (f32) -> coalesced BF16 row stores ----
  float* smf = (float*)smem;
  unsigned short* ob = av + (size_t)b * ((size_t)C_DIM * HW_DIM) +
                       (size_t)(cb * 256) * HW_DIM + nb * 256;
#pragma unroll
  for (int h = 0; h < 2; ++h) {
    if (wm == h) {
#pragma unroll
      for (int mi = 0; mi < 8; ++mi)
#pragma unroll
        for (int ni = 0; ni < 4; ++ni)
#pragma unroll
          for (int rr = 0; rr < 4; ++rr) {
            const int rloc = mi * 16 + kq * 4 + rr;  // 0..127
            const int col = wn * 64 + ni * 16 + rl;
            const int key = rloc & 7;
            smf[rloc * 256 + ((((col >> 2) ^ key) << 2) | (col & 3))] =
                acc[mi][ni][rr];
          }
    }
    __syncthreads();
#pragma unroll
    for (int it = 0; it < 16; ++it) {
      const int rloc = it * 8 + wave;
      const float4 vv =
          *(const float4*)(smf + rloc * 256 + ((lane ^ (rloc & 7)) << 2));
      v4us p;
      p[0] = f2bf(vv.x); p[1] = f2bf(vv.y);
      p[2] = f2bf(vv.z); p[3] = f2bf(vv.w);
      *(v4us*)(ob + (size_t)(h * 128 + rloc) * HW_DIM + lane * 4) = p;
    }
    __syncthreads();
  }
}

// ---------------- pass 4: LN over HW=4096, av bf16 + residual bf16 ----------
__global__ __launch_bounds__(256) void k_ln(
    float* __restrict__ out, const unsigned short* __restrict__ av,
    const unsigned short* __restrict__ vres,
    const float* __restrict__ gamma, const float* __restrict__ w,
    const float* __restrict__ bias) {
  const int row = blockIdx.x;  // 0..8191
  float* p = out + (size_t)row * HW_DIM;
  const unsigned short* ap = av + (size_t)row * HW_DIM;
  const unsigned short* vr = vres + (size_t)row * HW_DIM;
  const float g = gamma[0];
  const int tid = threadIdx.x;
  float4 vals[4];
  float s = 0.f, ss = 0.f;
#pragma unroll
  for (int i = 0; i < 4; ++i) {
    const int idx = tid + i * 256;
    const v4us au = *(const v4us*)(ap + idx * 4);
    const v4us rv = *(const v4us*)(vr + idx * 4);
    float4 vv;
    vv.x = g * bf2f(au[0]) + bf2f(rv[0]);
    vv.y = g * bf2f(au[1]) + bf2f(rv[1]);
    vv.z = g * bf2f(au[2]) + bf2f(rv[2]);
    vv.w = g * bf2f(au[3]) + bf2f(rv[3]);
    vals[i] = vv;
    s += vv.x + vv.y + vv.z + vv.w;
    ss += vv.x * vv.x + vv.y * vv.y + vv.z * vv.z + vv.w * vv.w;
  }
#pragma unroll
  for (int off = 32; off > 0; off >>= 1) {
    s += __shfl_xor(s, off);
    ss += __shfl_xor(ss, off);
  }
  __shared__ float rs[4], rss[4];
  const int wv = tid >> 6, ln = tid & 63;
  if (ln == 0) { rs[wv] = s; rss[wv] = ss; }
  __syncthreads();
  s = rs[0] + rs[1] + rs[2] + rs[3];
  ss = rss[0] + rss[1] + rss[2] + rss[3];
  const float mean = s * (1.f / HW_DIM);
  const float var = ss * (1.f / HW_DIM) - mean * mean;
  const float rstd = rsqrtf(var + LN_EPS);
#pragma unroll
  for (int i = 0; i < 4; ++i) {
    const int idx = tid + i * 256;
    const float4 vv = vals[i];
    const float4 w4 = ((const float4*)w)[idx];
    const float4 b4 = ((const float4*)bias)[idx];
    float4 r;
    r.x = (vv.x - mean) * rstd * w4.x + b4.x;
    r.y = (vv.y - mean) * rstd * w4.y + b4.y;
    r.z = (vv.z - mean) * rstd * w4.z + b4.z;
    r.w = (vv.w - mean) * rstd * w4.w + b4.w;
    ((float4*)p)[idx] = r;
  }
}

extern "C" void kernel_launch(void* const* d_in, const int* in_sizes, int n_in,
                              void* d_out, int out_size, void* d_ws, size_t ws_size,
                              hipStream_t stream) {
  const float* x = (const float*)d_in[0];
  const float* gamma = (const float*)d_in[1];
  const float* lnw = (const float*)d_in[2];
  const float* lnb = (const float*)d_in[3];
  float* out = (float*)d_out;
  char* ws = (char*)d_ws;

  const size_t n_elem = (size_t)B_DIM * C_DIM * HW_DIM;       // 33,554,432
  const size_t e_elems = (size_t)B_DIM * C_DIM * C_DIM;       // 4,194,304
  unsigned short* vbf = (unsigned short*)ws;                  // 64 MiB
  unsigned short* vbfT = (unsigned short*)(ws + 2 * n_elem);  // 64 MiB
  float* e_part = (float*)(ws + 4 * n_elem);                  // 4 x 16 MiB
  unsigned short* attn =
      (unsigned short*)(ws + 4 * n_elem + 4 * e_elems * sizeof(float));  // 8 MiB
  unsigned short* av = (unsigned short*)(ws + 4 * n_elem +
                                         4 * e_elems * sizeof(float) +
                                         2 * e_elems);        // 64 MiB

  k_convert_transpose<<<dim3(HW_DIM / 64, C_DIM / 64, B_DIM), 256, 0, stream>>>(
      x, vbf, vbfT);
  k_gemm1<<<256, 512, 0, stream>>>((const bf16*)vbf, e_part);
  k_softmax<<<B_DIM * C_DIM, 256, 0, stream>>>(e_part, attn);
  k_gemm2<<<512, 512, 0, stream>>>((const bf16*)attn, (const bf16*)vbfT, av);
  k_ln<<<B_DIM * C_DIM, 256, 0, stream>>>(out, av, vbf, gamma, lnw, lnb);
}